// Round 2
// baseline (142.347 us; speedup 1.0000x reference)
//
#include <hip/hip_runtime.h>
#include <math.h>

#define HW1 (1024 * 1024)
#define WID 1024
#define HEI 1024

// Block-level reduce (wave shfl + LDS) then one atomicAdd per block.
__device__ __forceinline__ void block_atomic_add(float v, float* target, volatile float* sdata) {
#pragma unroll
    for (int off = 32; off > 0; off >>= 1)
        v += __shfl_down(v, off, 64);
    const int lane = threadIdx.x & 63;
    const int wv   = threadIdx.x >> 6;
    if (lane == 0) sdata[wv] = v;
    __syncthreads();
    if (threadIdx.x == 0) {
        float s = 0.f;
        const int nw = blockDim.x >> 6;
        for (int i = 0; i < nw; ++i) s += sdata[i];
        atomicAdd(target, s);
    }
    __syncthreads();
}

// Main pass v2: one thread owns a 4x1 row strip (one y-row of a pool cell).
// Block: 256 threads = 64 pool-x cells (lane) x 4 y-rows (wave). Grid: 1024 blocks.
//  - c_loss: per-pixel batch/channel sums are fully thread-local (norm over batch dim)
//  - r_loss: thread-local partial
//  - pooled diff: per-plane row partials -> LDS -> y-reduction -> pool array
__global__ __launch_bounds__(256) void k_main(const float* __restrict__ A,
                                              const float* __restrict__ B,
                                              float* __restrict__ pool,
                                              float* __restrict__ acc) {
    const int tid   = threadIdx.x;
    const int xl    = tid & 63;          // pool-x within chunk
    const int yl    = tid >> 6;          // y-row within pool cell (0..3)
    const int gy    = blockIdx.x >> 2;   // pool-y 0..255
    const int chunk = blockIdx.x & 3;    // x chunk 0..3
    const int gx    = chunk * 64 + xl;   // pool-x 0..255
    const int px    = gx * 4;
    const int y     = gy * 4 + yl;

    __shared__ float pd_lds[24 * 4 * 64];   // [plane][yl][xl]
    __shared__ float s1[4], s2[4];

    float na2[12], nb2[12], dt[12];  // [c*4 + xi]
#pragma unroll
    for (int i = 0; i < 12; ++i) { na2[i] = 0.f; nb2[i] = 0.f; dt[i] = 0.f; }
    float r_sum = 0.f;

    const size_t rowoff = (size_t)y * WID + px;

#pragma unroll 2
    for (int b = 0; b < 8; ++b) {
#pragma unroll
        for (int c = 0; c < 3; ++c) {
            const int plane = b * 3 + c;
            const float4 a4 = *reinterpret_cast<const float4*>(A + (size_t)plane * HW1 + rowoff);
            const float4 b4 = *reinterpret_cast<const float4*>(B + (size_t)plane * HW1 + rowoff);
            float pd = 0.f;
            {
                float a = a4.x, t = b4.x;
                na2[c * 4 + 0] += a * a; nb2[c * 4 + 0] += t * t; dt[c * 4 + 0] += a * t;
                r_sum += fabsf(a - t); pd += t - a;
            }
            {
                float a = a4.y, t = b4.y;
                na2[c * 4 + 1] += a * a; nb2[c * 4 + 1] += t * t; dt[c * 4 + 1] += a * t;
                r_sum += fabsf(a - t); pd += t - a;
            }
            {
                float a = a4.z, t = b4.z;
                na2[c * 4 + 2] += a * a; nb2[c * 4 + 2] += t * t; dt[c * 4 + 2] += a * t;
                r_sum += fabsf(a - t); pd += t - a;
            }
            {
                float a = a4.w, t = b4.w;
                na2[c * 4 + 3] += a * a; nb2[c * 4 + 3] += t * t; dt[c * 4 + 3] += a * t;
                r_sum += fabsf(a - t); pd += t - a;
            }
            pd_lds[(plane * 4 + yl) * 64 + xl] = pd;
        }
    }
    __syncthreads();

    // y-reduce pooled diff and write pool: 24 planes x 64 x-cells = 1536 values, 256 threads
#pragma unroll
    for (int idx = tid; idx < 24 * 64; idx += 256) {
        const int plane = idx >> 6;
        const int x     = idx & 63;
        const float s = pd_lds[(plane * 4 + 0) * 64 + x] + pd_lds[(plane * 4 + 1) * 64 + x]
                      + pd_lds[(plane * 4 + 2) * 64 + x] + pd_lds[(plane * 4 + 3) * 64 + x];
        pool[(size_t)plane * 65536 + gy * 256 + chunk * 64 + x] = s * (1.0f / 16.0f);
    }

    // c_loss for this thread's 4 pixels
    float c_sum = 0.f;
#pragma unroll
    for (int xi = 0; xi < 4; ++xi) {
        float cs = 0.f;
#pragma unroll
        for (int c = 0; c < 3; ++c) {
            float na = fmaxf(sqrtf(na2[c * 4 + xi]), 1e-12f);
            float nb = fmaxf(sqrtf(nb2[c * 4 + xi]), 1e-12f);
            cs += dt[c * 4 + xi] / (na * nb);
        }
        cs = fminf(fmaxf(cs, -1.0f + 1e-7f), 1.0f - 1e-7f);
        c_sum += acosf(cs);
    }

    block_atomic_add(r_sum, acc + 0, s1);
    block_atomic_add(c_sum, acc + 1, s2);
}

// Sobel |grad| sum on batch-0 images. Column-sum decomposition:
// col[x] = d(y-1,x) + 2 d(y,x) + d(y+1,x);  out[x] = col[x-1] - col[x+1].
// Thread computes 4 consecutive outputs: 1 float4 + 2 halo scalars per row per array.
__global__ __launch_bounds__(256) void k_sobel(const float* __restrict__ A,
                                               const float* __restrict__ B,
                                               float* __restrict__ acc) {
    const int t   = blockIdx.x * 256 + threadIdx.x;  // 0 .. 786431
    const int x0  = (t & 255) * 4;
    const int rem = t >> 8;       // 0..3071
    const int y   = rem & 1023;
    const int c   = rem >> 10;    // 0..2

    const float* Ap = A + (size_t)c * HW1;
    const float* Bp = B + (size_t)c * HW1;

    float col[6];  // columns x0-1 .. x0+4 of the (1,2,1)-weighted row sum of d=A-B
#pragma unroll
    for (int j = 0; j < 6; ++j) col[j] = 0.f;

#pragma unroll
    for (int r = 0; r < 3; ++r) {
        const int yy = y - 1 + r;
        if (yy < 0 || yy >= HEI) continue;
        const float* ap = Ap + (size_t)yy * WID;
        const float* bp = Bp + (size_t)yy * WID;
        const float4 a4 = *reinterpret_cast<const float4*>(ap + x0);
        const float4 b4 = *reinterpret_cast<const float4*>(bp + x0);
        const float wr = (r == 1) ? 2.f : 1.f;
        col[1] += wr * (a4.x - b4.x);
        col[2] += wr * (a4.y - b4.y);
        col[3] += wr * (a4.z - b4.z);
        col[4] += wr * (a4.w - b4.w);
        if (x0 > 0)    col[0] += wr * (ap[x0 - 1] - bp[x0 - 1]);
        if (x0 < 1020) col[5] += wr * (ap[x0 + 4] - bp[x0 + 4]);
    }

    float s = fabsf(col[0] - col[2]) + fabsf(col[1] - col[3])
            + fabsf(col[2] - col[4]) + fabsf(col[3] - col[5]);

    __shared__ float sd[4];
    block_atomic_add(s, acc + 2, sd);
}

// Spatial-consistency loss from pooled diff array P[24][256][256].
__global__ __launch_bounds__(256) void k_spa(const float* __restrict__ P,
                                             float* __restrict__ acc) {
    const int t = blockIdx.x * 256 + threadIdx.x;  // 0 .. 524287
    const int x = t & 255;
    const int y = (t >> 8) & 255;
    const int b = t >> 16;  // 0..7

    const float* Rr = P + (size_t)(b * 3 + 0) * 65536 + y * 256;
    const float* Gg = P + (size_t)(b * 3 + 1) * 65536 + y * 256;
    const float* Bb = P + (size_t)(b * 3 + 2) * 65536 + y * 256;

    const float g  = Gg[x];
    const float gl = (x > 0)   ? Gg[x - 1] : 0.f;
    const float gr = (x < 255) ? Gg[x + 1] : 0.f;
    const float d0 = g - gl;
    const float d1 = g - gr;
    const float d2 = g - Rr[x];
    const float d3 = g - Bb[x];
    float s = d0 * d0 + d1 * d1 + d2 * d2 + d3 * d3;

    __shared__ float sd[4];
    block_atomic_add(s, acc + 3, sd);
}

// Combine: out = W_C*c + W_R*r + W_P*p + W_S*s
__global__ void k_final(const float* __restrict__ acc, float* __restrict__ out) {
    const float r = acc[0] * (1.0f / 25165824.0f);  // mean over 8*3*1024*1024
    const float c = acc[1];
    const float s = acc[2];
    const float p = acc[3] * (1.0f / 524288.0f);    // mean over 8*256*256
    out[0] = 0.5f * c + 1.0f * r + 1.0f * p + 0.1f * s;
}

extern "C" void kernel_launch(void* const* d_in, const int* in_sizes, int n_in,
                              void* d_out, int out_size, void* d_ws, size_t ws_size,
                              hipStream_t stream) {
    const float* A = (const float*)d_in[0];  // predictions
    const float* B = (const float*)d_in[1];  // targets
    float* acc  = (float*)d_ws;              // 4 accumulators (+ padding)
    float* pool = (float*)d_ws + 64;         // 8*3*256*256 floats = 6.29 MB

    hipMemsetAsync(d_ws, 0, 64 * sizeof(float), stream);

    hipLaunchKernelGGL(k_main,  dim3(1024), dim3(256), 0, stream, A, B, pool, acc);
    hipLaunchKernelGGL(k_sobel, dim3(3072), dim3(256), 0, stream, A, B, acc);
    hipLaunchKernelGGL(k_spa,   dim3(2048), dim3(256), 0, stream, pool, acc);
    hipLaunchKernelGGL(k_final, dim3(1),    dim3(1),   0, stream, acc, (float*)d_out);
}